// Round 10
// baseline (396.495 us; speedup 1.0000x reference)
//
#include <hip/hip_runtime.h>
#include <cstddef>

#define N_NODES 50000
#define N_EDGES 800000
#define NBUK    196        // dst/src buckets of 256 nodes
#define NBLK    256        // edge-slice blocks
#define EPB     3125       // edges per slice block (256*3125 = 800000)
#define HEAD_BLOCKS 3136

typedef unsigned u32;
typedef unsigned short u16;
typedef unsigned char u8;
typedef __attribute__((ext_vector_type(8))) short bf16x8;
typedef __attribute__((ext_vector_type(4))) float f32x4;

__device__ __forceinline__ float bflo(u32 u) { return __uint_as_float(u << 16); }
__device__ __forceinline__ float bfhi(u32 u) { return __uint_as_float(u & 0xFFFF0000u); }
__device__ __forceinline__ u32 f2bf(float f) {            // RNE round to bf16
    u32 u = __float_as_uint(f);
    return (u + 0x7FFFu + ((u >> 16) & 1u)) >> 16;
}
__device__ __forceinline__ u32 packbf2(float a, float b) { return f2bf(a) | (f2bf(b) << 16); }

// ---------- byte offsets in workspace ----------
#define OFF_NS    0u          // f32[50000]
#define OFF_ND    200000u     // f32[50000]
#define OFF_RS    400000u     // u32[50001]
#define OFF_ES    600016u     // u16[800000]
#define OFF_CNTD  2200016u    // u32[NBLK*NBUK]
#define OFF_CNTS  2400720u    // u32[NBLK*NBUK]
#define OFF_TOTD  2601424u    // u32[NBUK]
#define OFF_TOTS  2602208u    // u32[NBUK]
#define OFF_BASED 2602992u    // u32[NBUK]
#define OFF_BASES 2603776u    // u32[NBUK]
#define OFF_VP    2604560u    // f32[HEAD_BLOCKS]
#define OFF_DB    2617104u    // u32[800000]  packed (src<<8)|dst_low
#define OFF_SB    5817104u    // u8 [800000]  src_low
#define OFF_T0    6617104u    // bf16[50000*128]
#define OFF_T1    19417104u   // bf16[50000*128]
#define OFF_T2    32217104u   // bf16[50000*128]
#define OFF_TT    45017104u   // bf16[50000*64]
#define OFF_WT    51417104u   // bf16: W0t,W1t,W2t (each 128*128) + W3t (64*128)
// end 51531792 B

// ---- phase 1: per-slice bucket counts
__global__ __launch_bounds__(256)
void p1_kernel(const int* __restrict__ src, const int* __restrict__ dst,
               u32* __restrict__ cntD, u32* __restrict__ cntS) {
    __shared__ u32 dc[NBUK], sc[NBUK];
    int b = blockIdx.x, tid = threadIdx.x;
    if (tid < NBUK) { dc[tid] = 0; sc[tid] = 0; }
    __syncthreads();
    int lo = b * EPB, hi = lo + EPB;
    for (int e = lo + tid; e < hi; e += 256) {
        atomicAdd(&dc[dst[e] >> 8], 1u);
        atomicAdd(&sc[src[e] >> 8], 1u);
    }
    __syncthreads();
    if (tid < NBUK) {
        cntD[b * NBUK + tid] = dc[tid];
        cntS[b * NBUK + tid] = sc[tid];
    }
}

// ---- phase 2a: per-bucket scan over slice counts
__global__ __launch_bounds__(256)
void p2a_kernel(u32* __restrict__ cntD, u32* __restrict__ cntS,
                u32* __restrict__ totD, u32* __restrict__ totS) {
    __shared__ u32 sc[256];
    int k = blockIdx.x, tid = threadIdx.x;
    u32 v = cntD[tid * NBUK + k];
    sc[tid] = v;
    __syncthreads();
    for (int o = 1; o < 256; o <<= 1) {
        u32 t = (tid >= o) ? sc[tid - o] : 0u;
        __syncthreads(); sc[tid] += t; __syncthreads();
    }
    cntD[tid * NBUK + k] = sc[tid] - v;
    if (tid == 255) totD[k] = sc[255];
    __syncthreads();
    v = cntS[tid * NBUK + k];
    sc[tid] = v;
    __syncthreads();
    for (int o = 1; o < 256; o <<= 1) {
        u32 t = (tid >= o) ? sc[tid - o] : 0u;
        __syncthreads(); sc[tid] += t; __syncthreads();
    }
    cntS[tid * NBUK + k] = sc[tid] - v;
    if (tid == 255) totS[k] = sc[255];
}

// ---- phase 2b: bucket base offsets
__global__ __launch_bounds__(256)
void p2b_kernel(const u32* __restrict__ totD, const u32* __restrict__ totS,
                u32* __restrict__ baseD, u32* __restrict__ baseS, u32* __restrict__ rs) {
    __shared__ u32 sc[256];
    int tid = threadIdx.x;
    u32 v = (tid < NBUK) ? totD[tid] : 0u;
    sc[tid] = v;
    __syncthreads();
    for (int o = 1; o < 256; o <<= 1) {
        u32 t = (tid >= o) ? sc[tid - o] : 0u;
        __syncthreads(); sc[tid] += t; __syncthreads();
    }
    if (tid < NBUK) baseD[tid] = sc[tid] - v;
    __syncthreads();
    v = (tid < NBUK) ? totS[tid] : 0u;
    sc[tid] = v;
    __syncthreads();
    for (int o = 1; o < 256; o <<= 1) {
        u32 t = (tid >= o) ? sc[tid - o] : 0u;
        __syncthreads(); sc[tid] += t; __syncthreads();
    }
    if (tid < NBUK) baseS[tid] = sc[tid] - v;
    if (tid == 0) rs[N_NODES] = N_EDGES;
}

// ---- phase 3: place edges into bucket runs
__global__ __launch_bounds__(256)
void p3_kernel(const int* __restrict__ src, const int* __restrict__ dst,
               const u32* __restrict__ cntD, const u32* __restrict__ cntS,
               const u32* __restrict__ baseD, const u32* __restrict__ baseS,
               u32* __restrict__ db, u8* __restrict__ sb) {
    __shared__ u32 od[NBUK], os[NBUK];
    int b = blockIdx.x, tid = threadIdx.x;
    if (tid < NBUK) {
        od[tid] = baseD[tid] + cntD[b * NBUK + tid];
        os[tid] = baseS[tid] + cntS[b * NBUK + tid];
    }
    __syncthreads();
    int lo = b * EPB, hi = lo + EPB;
    for (int e = lo + tid; e < hi; e += 256) {
        int s = src[e], d = dst[e];
        u32 p = atomicAdd(&od[d >> 8], 1u);
        db[p] = ((u32)s << 8) | (u32)(d & 255);
        u32 q = atomicAdd(&os[s >> 8], 1u);
        sb[q] = (u8)(s & 255);
    }
}

// ---- phase 4d: per-bucket CSR finalize
__global__ __launch_bounds__(256)
void p4d_kernel(const u32* __restrict__ db, const u32* __restrict__ totD,
                const u32* __restrict__ baseD, float* __restrict__ nd,
                u32* __restrict__ rs, u16* __restrict__ es) {
    __shared__ u32 hist[256], sc[256], off[256];
    int k = blockIdx.x, tid = threadIdx.x;
    hist[tid] = 0;
    __syncthreads();
    u32 nEd = totD[k], base = baseD[k];
    for (u32 i = tid; i < nEd; i += 256)
        atomicAdd(&hist[db[base + i] & 255u], 1u);
    __syncthreads();
    u32 v = hist[tid];
    sc[tid] = v;
    __syncthreads();
    for (int o = 1; o < 256; o <<= 1) {
        u32 t = (tid >= o) ? sc[tid - o] : 0u;
        __syncthreads(); sc[tid] += t; __syncthreads();
    }
    u32 pf = sc[tid] - v;
    int node = k * 256 + tid;
    if (node < N_NODES) {
        rs[node] = base + pf;
        u32 c = v < 1u ? 1u : v;
        nd[node] = rsqrtf((float)c);
    }
    off[tid] = base + pf;
    __syncthreads();
    for (u32 i = tid; i < nEd; i += 256) {
        u32 p = db[base + i];
        u32 pos = atomicAdd(&off[p & 255u], 1u);
        es[pos] = (u16)(p >> 8);
    }
}

// ---- phase 4s + prescale fused
__global__ __launch_bounds__(256)
void p4sp_kernel(const u8* __restrict__ sb, const u32* __restrict__ totS,
                 const u32* __restrict__ baseS, float* __restrict__ ns,
                 const float* __restrict__ feat, u16* __restrict__ hS) {
    __shared__ u32 hist[256];
    __shared__ float sns[256];
    int k = blockIdx.x, tid = threadIdx.x;
    hist[tid] = 0;
    __syncthreads();
    u32 n = totS[k], base = baseS[k];
    for (u32 i = tid; i < n; i += 256)
        atomicAdd(&hist[sb[base + i]], 1u);
    __syncthreads();
    int node = k * 256 + tid;
    {
        u32 c = hist[tid]; if (c < 1u) c = 1u;
        float s = rsqrtf((float)c);
        sns[tid] = s;
        if (node < N_NODES) ns[node] = s;
    }
    __syncthreads();
    for (int i = tid; i < 256 * 32; i += 256) {
        int r = i >> 5, c4 = i & 31;
        int g = k * 256 + r;
        if (g >= N_NODES) break;
        float s = sns[r];
        float4 v = *(const float4*)&feat[(size_t)g * 128 + c4 * 4];
        uint2 o;
        o.x = packbf2(s * v.x, s * v.y);
        o.y = packbf2(s * v.z, s * v.w);
        *(uint2*)&hS[(size_t)g * 128 + c4 * 4] = o;
    }
}

// ---- W -> bf16 transposed tables: WtL[c*128+k] = bf16(WL[k][c])
__global__ __launch_bounds__(256)
void wconv_kernel(const float* __restrict__ W0, const float* __restrict__ W1,
                  const float* __restrict__ W2, const float* __restrict__ W3,
                  u16* __restrict__ wt) {
    int i = blockIdx.x * 256 + threadIdx.x;
    if (i < 49152) {                      // layers 0..2, 128x128 each
        int l = i / 16384, r = i % 16384;
        int c = r >> 7, k = r & 127;
        const float* W = (l == 0) ? W0 : (l == 1) ? W1 : W2;
        wt[l * 16384 + r] = (u16)f2bf(W[k * 128 + c]);
    } else if (i < 49152 + 8192) {        // layer 3, 128x64
        int r = i - 49152;
        int c = r >> 7, k = r & 127;
        wt[49152 + r] = (u16)f2bf(W3[k * 64 + c]);
    }
}

// ---- FUSED gather-aggregate + MFMA GEMM (hidden layers, 128->128)
// block = 256 thr (4 waves), 32 rows; wave gathers 8 nodes into LDS,
// then MFMA: wave w = m-tile (w>>1), col-half (w&1); B-frags from global wt.
// C = ns*relu(nd*acc + b), bf16 out.
__global__ __launch_bounds__(256)
void aggmm_kernel(const u16* __restrict__ h, const u32* __restrict__ rs,
                  const u16* __restrict__ es, const u16* __restrict__ wt,
                  const float* __restrict__ bias, const float* __restrict__ ns,
                  const float* __restrict__ nd, u16* __restrict__ C) {
    __shared__ u16 As[32 * 136];
    int tid = threadIdx.x;
    int w = tid >> 6, lane = tid & 63;
    int quarter = lane >> 4, q = lane & 15;
    int rowbase = blockIdx.x * 32;
    const uint4* hp = (const uint4*)h;    // table row = 16 uint4

    // ---- gather: wave w fills LDS rows w*8 .. w*8+7
    for (int j = 0; j < 8; ++j) {
        int lr = w * 8 + j;
        int node = rowbase + lr;
        float acc[8] = {0.f, 0.f, 0.f, 0.f, 0.f, 0.f, 0.f, 0.f};
        if (node < N_NODES) {
            u32 s0 = rs[node], s1 = rs[node + 1];
            u32 i = s0;
            for (; i + 16 <= s1; i += 16) {
                int e0 = es[i + quarter],     e1 = es[i + 4 + quarter];
                int e2 = es[i + 8 + quarter], e3 = es[i + 12 + quarter];
                uint4 a = hp[(size_t)e0 * 16 + q];
                uint4 b = hp[(size_t)e1 * 16 + q];
                uint4 c = hp[(size_t)e2 * 16 + q];
                uint4 d = hp[(size_t)e3 * 16 + q];
                acc[0] += (bflo(a.x) + bflo(b.x)) + (bflo(c.x) + bflo(d.x));
                acc[1] += (bfhi(a.x) + bfhi(b.x)) + (bfhi(c.x) + bfhi(d.x));
                acc[2] += (bflo(a.y) + bflo(b.y)) + (bflo(c.y) + bflo(d.y));
                acc[3] += (bfhi(a.y) + bfhi(b.y)) + (bfhi(c.y) + bfhi(d.y));
                acc[4] += (bflo(a.z) + bflo(b.z)) + (bflo(c.z) + bflo(d.z));
                acc[5] += (bfhi(a.z) + bfhi(b.z)) + (bfhi(c.z) + bfhi(d.z));
                acc[6] += (bflo(a.w) + bflo(b.w)) + (bflo(c.w) + bflo(d.w));
                acc[7] += (bfhi(a.w) + bfhi(b.w)) + (bfhi(c.w) + bfhi(d.w));
            }
            for (; i + 4 <= s1; i += 4) {
                uint4 a = hp[(size_t)es[i + quarter] * 16 + q];
                acc[0] += bflo(a.x); acc[1] += bfhi(a.x);
                acc[2] += bflo(a.y); acc[3] += bfhi(a.y);
                acc[4] += bflo(a.z); acc[5] += bfhi(a.z);
                acc[6] += bflo(a.w); acc[7] += bfhi(a.w);
            }
            u32 rem = s1 - i;
            if ((u32)quarter < rem) {
                uint4 a = hp[(size_t)es[i + quarter] * 16 + q];
                acc[0] += bflo(a.x); acc[1] += bfhi(a.x);
                acc[2] += bflo(a.y); acc[3] += bfhi(a.y);
                acc[4] += bflo(a.z); acc[5] += bfhi(a.z);
                acc[6] += bflo(a.w); acc[7] += bfhi(a.w);
            }
        }
        #pragma unroll
        for (int jj = 0; jj < 8; ++jj) {
            acc[jj] += __shfl_xor(acc[jj], 16, 64);
            acc[jj] += __shfl_xor(acc[jj], 32, 64);
        }
        if (lane < 16) {
            uint4 pk;
            pk.x = packbf2(acc[0], acc[1]);
            pk.y = packbf2(acc[2], acc[3]);
            pk.z = packbf2(acc[4], acc[5]);
            pk.w = packbf2(acc[6], acc[7]);
            *(uint4*)&As[lr * 136 + q * 8] = pk;
        }
    }
    __syncthreads();

    // ---- MFMA: wave w -> rows (w>>1)*16..+15, cols (w&1)*64..+63
    int m = lane & 15, kb = lane >> 4;
    int mtile = w >> 1, nhalf = w & 1;
    f32x4 acc[4];
    #pragma unroll
    for (int nt = 0; nt < 4; ++nt) acc[nt] = (f32x4){0.f, 0.f, 0.f, 0.f};
    #pragma unroll
    for (int ks = 0; ks < 4; ++ks) {
        int k0 = ks * 32 + kb * 8;
        bf16x8 a = *(const bf16x8*)&As[(mtile * 16 + m) * 136 + k0];
        #pragma unroll
        for (int nt = 0; nt < 4; ++nt) {
            int c = nhalf * 64 + nt * 16 + m;
            bf16x8 b = *(const bf16x8*)&wt[(size_t)c * 128 + k0];
            acc[nt] = __builtin_amdgcn_mfma_f32_16x16x32_bf16(a, b, acc[nt], 0, 0, 0);
        }
    }
    // ---- epilogue: pair-pack via shfl, 4B stores
    #pragma unroll
    for (int nt = 0; nt < 4; ++nt) {
        int c = nhalf * 64 + nt * 16 + m;
        float bs = bias[c];
        #pragma unroll
        for (int reg = 0; reg < 4; ++reg) {
            int row = rowbase + mtile * 16 + kb * 4 + reg;
            int rc = row < N_NODES ? row : N_NODES - 1;
            float o = ns[rc] * fmaxf(nd[rc] * acc[nt][reg] + bs, 0.f);
            float o2 = __shfl_xor(o, 1, 64);
            if (!(m & 1) && row < N_NODES)
                *(u32*)&C[(size_t)row * 128 + c] = packbf2(o, o2);
        }
    }
}

// ---- layer-3 transform: T (bf16 [N][128]) @ W3t -> Tt (bf16 [N][64]), no LDS
__global__ __launch_bounds__(256)
void tf64_kernel(const u16* __restrict__ Ain, const u16* __restrict__ wt,
                 u16* __restrict__ Cout) {
    int tid = threadIdx.x;
    int w = tid >> 6, lane = tid & 63;
    int m = lane & 15, kb = lane >> 4;
    int mtile = w >> 1, nhalf = w & 1;
    int rowbase = blockIdx.x * 32;
    int arow = rowbase + mtile * 16 + m;
    if (arow > N_NODES - 1) arow = N_NODES - 1;
    f32x4 acc[2];
    acc[0] = (f32x4){0.f, 0.f, 0.f, 0.f};
    acc[1] = (f32x4){0.f, 0.f, 0.f, 0.f};
    #pragma unroll
    for (int ks = 0; ks < 4; ++ks) {
        int k0 = ks * 32 + kb * 8;
        bf16x8 a = *(const bf16x8*)&Ain[(size_t)arow * 128 + k0];
        #pragma unroll
        for (int nt = 0; nt < 2; ++nt) {
            int c = nhalf * 32 + nt * 16 + m;
            bf16x8 b = *(const bf16x8*)&wt[(size_t)c * 128 + k0];
            acc[nt] = __builtin_amdgcn_mfma_f32_16x16x32_bf16(a, b, acc[nt], 0, 0, 0);
        }
    }
    #pragma unroll
    for (int nt = 0; nt < 2; ++nt) {
        int c = nhalf * 32 + nt * 16 + m;
        #pragma unroll
        for (int reg = 0; reg < 4; ++reg) {
            int row = rowbase + mtile * 16 + kb * 4 + reg;
            float o = acc[nt][reg];
            float o2 = __shfl_xor(o, 1, 64);
            if (!(m & 1) && row < N_NODES)
                *(u32*)&Cout[(size_t)row * 64 + c] = packbf2(o, o2);
        }
    }
}

// ---- fused layer-3 aggregate + heads
__global__ __launch_bounds__(256)
void l3head_kernel(const u16* __restrict__ t, const u32* __restrict__ rs,
                   const u16* __restrict__ es, const float* __restrict__ nd,
                   const float* __restrict__ b3, const float* __restrict__ Wp,
                   const float* __restrict__ Wv, const float* __restrict__ bp,
                   float* __restrict__ out, float* __restrict__ vpart) {
    __shared__ float sv;
    if (threadIdx.x == 0) sv = 0.f;
    __syncthreads();
    int lane = threadIdx.x & 63;
    int wvid = threadIdx.x >> 6;
    int oct = lane >> 3;
    int q = lane & 7;
    const uint4* hp = (const uint4*)t;     // row = 8 uint4
    float4 b3a = ((const float4*)b3)[q * 2];
    float4 b3b = ((const float4*)b3)[q * 2 + 1];
    float4 wpa = ((const float4*)Wp)[q * 2];
    float4 wpb = ((const float4*)Wp)[q * 2 + 1];
    float4 wva = ((const float4*)Wv)[q * 2];
    float4 wvb = ((const float4*)Wv)[q * 2 + 1];
    float bpv = bp[0];
    float vacc = 0.f;
    for (int n = blockIdx.x * 4 + wvid; n < N_NODES; n += HEAD_BLOCKS * 4) {
        u32 s0 = rs[n], s1 = rs[n + 1];
        float acc[8] = {0.f, 0.f, 0.f, 0.f, 0.f, 0.f, 0.f, 0.f};
        u32 i = s0;
        for (; i + 32 <= s1; i += 32) {
            int e0 = es[i + oct],      e1 = es[i + 8 + oct];
            int e2 = es[i + 16 + oct], e3 = es[i + 24 + oct];
            uint4 a = hp[(size_t)e0 * 8 + q];
            uint4 bb = hp[(size_t)e1 * 8 + q];
            uint4 c = hp[(size_t)e2 * 8 + q];
            uint4 d = hp[(size_t)e3 * 8 + q];
            acc[0] += (bflo(a.x) + bflo(bb.x)) + (bflo(c.x) + bflo(d.x));
            acc[1] += (bfhi(a.x) + bfhi(bb.x)) + (bfhi(c.x) + bfhi(d.x));
            acc[2] += (bflo(a.y) + bflo(bb.y)) + (bflo(c.y) + bflo(d.y));
            acc[3] += (bfhi(a.y) + bfhi(bb.y)) + (bfhi(c.y) + bfhi(d.y));
            acc[4] += (bflo(a.z) + bflo(bb.z)) + (bflo(c.z) + bflo(d.z));
            acc[5] += (bfhi(a.z) + bfhi(bb.z)) + (bfhi(c.z) + bfhi(d.z));
            acc[6] += (bflo(a.w) + bflo(bb.w)) + (bflo(c.w) + bflo(d.w));
            acc[7] += (bfhi(a.w) + bfhi(bb.w)) + (bfhi(c.w) + bfhi(d.w));
        }
        for (; i + 8 <= s1; i += 8) {
            uint4 a = hp[(size_t)es[i + oct] * 8 + q];
            acc[0] += bflo(a.x); acc[1] += bfhi(a.x);
            acc[2] += bflo(a.y); acc[3] += bfhi(a.y);
            acc[4] += bflo(a.z); acc[5] += bfhi(a.z);
            acc[6] += bflo(a.w); acc[7] += bfhi(a.w);
        }
        u32 rem = s1 - i;
        if ((u32)oct < rem) {
            uint4 a = hp[(size_t)es[i + oct] * 8 + q];
            acc[0] += bflo(a.x); acc[1] += bfhi(a.x);
            acc[2] += bflo(a.y); acc[3] += bfhi(a.y);
            acc[4] += bflo(a.z); acc[5] += bfhi(a.z);
            acc[6] += bflo(a.w); acc[7] += bfhi(a.w);
        }
        #pragma unroll
        for (int j = 0; j < 8; ++j) {
            acc[j] += __shfl_xor(acc[j], 8, 64);
            acc[j] += __shfl_xor(acc[j], 16, 64);
            acc[j] += __shfl_xor(acc[j], 32, 64);
        }
        float ndv = nd[n];
        float h0 = ndv * acc[0] + b3a.x, h1 = ndv * acc[1] + b3a.y;
        float h2 = ndv * acc[2] + b3a.z, h3 = ndv * acc[3] + b3a.w;
        float h4 = ndv * acc[4] + b3b.x, h5 = ndv * acc[5] + b3b.y;
        float h6 = ndv * acc[6] + b3b.z, h7 = ndv * acc[7] + b3b.w;
        float p  = h0 * wpa.x + h1 * wpa.y + h2 * wpa.z + h3 * wpa.w
                 + h4 * wpb.x + h5 * wpb.y + h6 * wpb.z + h7 * wpb.w;
        float vv = h0 * wva.x + h1 * wva.y + h2 * wva.z + h3 * wva.w
                 + h4 * wvb.x + h5 * wvb.y + h6 * wvb.z + h7 * wvb.w;
        p  += __shfl_xor(p, 1, 64);  p  += __shfl_xor(p, 2, 64);  p  += __shfl_xor(p, 4, 64);
        vv += __shfl_xor(vv, 1, 64); vv += __shfl_xor(vv, 2, 64); vv += __shfl_xor(vv, 4, 64);
        if (lane == 0) { out[n] = p + bpv; vacc += vv; }
    }
    if (lane == 0) atomicAdd(&sv, vacc);
    __syncthreads();
    if (threadIdx.x == 0) vpart[blockIdx.x] = sv;
}

// ---- final V reduction
__global__ __launch_bounds__(256)
void vred_kernel(const float* __restrict__ vpart, const float* __restrict__ bv,
                 float* __restrict__ out) {
    float v = 0.f;
    for (int i = threadIdx.x; i < HEAD_BLOCKS; i += 256) v += vpart[i];
    #pragma unroll
    for (int off = 32; off; off >>= 1) v += __shfl_down(v, off, 64);
    __shared__ float s[4];
    if ((threadIdx.x & 63) == 0) s[threadIdx.x >> 6] = v;
    __syncthreads();
    if (threadIdx.x == 0) out[N_NODES] = s[0] + s[1] + s[2] + s[3] + bv[0];
}

extern "C" void kernel_launch(void* const* d_in, const int* in_sizes, int n_in,
                              void* d_out, int out_size, void* d_ws, size_t ws_size,
                              hipStream_t stream) {
    const float* feat = (const float*)d_in[0];
    const int*   src  = (const int*)d_in[1];
    const int*   dst  = (const int*)d_in[2];
    const float* W0 = (const float*)d_in[3];  const float* b0 = (const float*)d_in[4];
    const float* W1 = (const float*)d_in[5];  const float* b1 = (const float*)d_in[6];
    const float* W2 = (const float*)d_in[7];  const float* b2 = (const float*)d_in[8];
    const float* W3 = (const float*)d_in[9];  const float* b3 = (const float*)d_in[10];
    const float* Wp = (const float*)d_in[11]; const float* bp = (const float*)d_in[12];
    const float* Wv = (const float*)d_in[13]; const float* bv = (const float*)d_in[14];
    float* out = (float*)d_out;
    char*  wsb = (char*)d_ws;

    float* ns    = (float*)(wsb + OFF_NS);
    float* nd    = (float*)(wsb + OFF_ND);
    u32*   rs    = (u32*)(wsb + OFF_RS);
    u16*   es    = (u16*)(wsb + OFF_ES);
    u32*   cntD  = (u32*)(wsb + OFF_CNTD);
    u32*   cntS  = (u32*)(wsb + OFF_CNTS);
    u32*   totD  = (u32*)(wsb + OFF_TOTD);
    u32*   totS  = (u32*)(wsb + OFF_TOTS);
    u32*   baseD = (u32*)(wsb + OFF_BASED);
    u32*   baseS = (u32*)(wsb + OFF_BASES);
    float* vpart = (float*)(wsb + OFF_VP);
    u32*   db    = (u32*)(wsb + OFF_DB);
    u8*    sb    = (u8*)(wsb + OFF_SB);
    u16*   T0    = (u16*)(wsb + OFF_T0);
    u16*   T1    = (u16*)(wsb + OFF_T1);
    u16*   T2    = (u16*)(wsb + OFF_T2);
    u16*   Tt    = (u16*)(wsb + OFF_TT);
    u16*   wt    = (u16*)(wsb + OFF_WT);

    wconv_kernel<<<224, 256, 0, stream>>>(W0, W1, W2, W3, wt);
    p1_kernel<<<NBLK, 256, 0, stream>>>(src, dst, cntD, cntS);
    p2a_kernel<<<NBUK, 256, 0, stream>>>(cntD, cntS, totD, totS);
    p2b_kernel<<<1, 256, 0, stream>>>(totD, totS, baseD, baseS, rs);
    p3_kernel<<<NBLK, 256, 0, stream>>>(src, dst, cntD, cntS, baseD, baseS, db, sb);
    p4d_kernel<<<NBUK, 256, 0, stream>>>(db, totD, baseD, nd, rs, es);
    p4sp_kernel<<<NBUK, 256, 0, stream>>>(sb, totS, baseS, ns, feat, T0);

    // fused layers: gather+GEMM per 32-row tile
    aggmm_kernel<<<1563, 256, 0, stream>>>(T0, rs, es, wt,          b0, ns, nd, T1);
    aggmm_kernel<<<1563, 256, 0, stream>>>(T1, rs, es, wt + 16384,  b1, ns, nd, T2);
    aggmm_kernel<<<1563, 256, 0, stream>>>(T2, rs, es, wt + 32768,  b2, ns, nd, T0);
    // layer 3: transform first (128->64), then fused aggregate+heads
    tf64_kernel<<<1563, 256, 0, stream>>>(T0, wt + 49152, Tt);
    l3head_kernel<<<HEAD_BLOCKS, 256, 0, stream>>>(Tt, rs, es, nd, b3, Wp, Wv, bp, out, vpart);
    vred_kernel<<<1, 256, 0, stream>>>(vpart, bv, out);
}

// Round 11
// 343.572 us; speedup vs baseline: 1.1540x; 1.1540x over previous
//
#include <hip/hip_runtime.h>
#include <cstddef>

#define N_NODES 50000
#define N_EDGES 800000
#define NBUK    196        // dst/src buckets of 256 nodes
#define NBLK    256        // edge-slice blocks
#define EPB     3125       // edges per slice block (256*3125 = 800000)
#define HEAD_BLOCKS 3136

typedef unsigned u32;
typedef unsigned short u16;
typedef __attribute__((ext_vector_type(8))) short bf16x8;
typedef __attribute__((ext_vector_type(4))) float f32x4;

__device__ __forceinline__ float bflo(u32 u) { return __uint_as_float(u << 16); }
__device__ __forceinline__ float bfhi(u32 u) { return __uint_as_float(u & 0xFFFF0000u); }
__device__ __forceinline__ u32 f2bf(float f) {            // RNE round to bf16
    u32 u = __float_as_uint(f);
    return (u + 0x7FFFu + ((u >> 16) & 1u)) >> 16;
}
__device__ __forceinline__ u32 packbf2(float a, float b) { return f2bf(a) | (f2bf(b) << 16); }

// ---------- byte offsets in workspace ----------
#define OFF_NS    0u          // f32[50000]
#define OFF_ND    200000u     // f32[50000]
#define OFF_RS    400000u     // u32[50001]
#define OFF_ES    600016u     // int[800000]
#define OFF_CNTD  3800016u    // u32[NBLK*NBUK]
#define OFF_CNTS  4000720u    // u32[NBLK*NBUK]
#define OFF_TOTD  4201424u    // u32[NBUK]
#define OFF_TOTS  4202208u    // u32[NBUK]
#define OFF_BASED 4202992u    // u32[NBUK]
#define OFF_BASES 4203776u    // u32[NBUK]
#define OFF_VP    4204560u    // f32[HEAD_BLOCKS] block partials for V
#define OFF_DB    4217104u    // int2[800000]
#define OFF_SB    10617104u   // int [800000]
#define OFF_T0    13817104u   // bf16[50000*128]
#define OFF_T1    26617104u   // bf16[50000*128]
#define OFF_TA    39417104u   // bf16[50000*128]  (agg output)
#define OFF_TT    52217104u   // bf16[50000*64]
// end 58617104 B

// ---- phase 1: per-slice bucket counts (LDS histogram, no global atomics)
__global__ __launch_bounds__(256)
void p1_kernel(const int* __restrict__ src, const int* __restrict__ dst,
               u32* __restrict__ cntD, u32* __restrict__ cntS) {
    __shared__ u32 dc[NBUK], sc[NBUK];
    int b = blockIdx.x, tid = threadIdx.x;
    if (tid < NBUK) { dc[tid] = 0; sc[tid] = 0; }
    __syncthreads();
    int lo = b * EPB, hi = lo + EPB;
    for (int e = lo + tid; e < hi; e += 256) {
        atomicAdd(&dc[dst[e] >> 8], 1u);
        atomicAdd(&sc[src[e] >> 8], 1u);
    }
    __syncthreads();
    if (tid < NBUK) {
        cntD[b * NBUK + tid] = dc[tid];
        cntS[b * NBUK + tid] = sc[tid];
    }
}

// ---- phase 2a: per-bucket scan over the 256 slice counts (in place -> exclusive)
__global__ __launch_bounds__(256)
void p2a_kernel(u32* __restrict__ cntD, u32* __restrict__ cntS,
                u32* __restrict__ totD, u32* __restrict__ totS) {
    __shared__ u32 sc[256];
    int k = blockIdx.x, tid = threadIdx.x;
    u32 v = cntD[tid * NBUK + k];
    sc[tid] = v;
    __syncthreads();
    for (int o = 1; o < 256; o <<= 1) {
        u32 t = (tid >= o) ? sc[tid - o] : 0u;
        __syncthreads(); sc[tid] += t; __syncthreads();
    }
    cntD[tid * NBUK + k] = sc[tid] - v;
    if (tid == 255) totD[k] = sc[255];
    __syncthreads();
    v = cntS[tid * NBUK + k];
    sc[tid] = v;
    __syncthreads();
    for (int o = 1; o < 256; o <<= 1) {
        u32 t = (tid >= o) ? sc[tid - o] : 0u;
        __syncthreads(); sc[tid] += t; __syncthreads();
    }
    cntS[tid * NBUK + k] = sc[tid] - v;
    if (tid == 255) totS[k] = sc[255];
}

// ---- phase 2b: bucket base offsets
__global__ __launch_bounds__(256)
void p2b_kernel(const u32* __restrict__ totD, const u32* __restrict__ totS,
                u32* __restrict__ baseD, u32* __restrict__ baseS, u32* __restrict__ rs) {
    __shared__ u32 sc[256];
    int tid = threadIdx.x;
    u32 v = (tid < NBUK) ? totD[tid] : 0u;
    sc[tid] = v;
    __syncthreads();
    for (int o = 1; o < 256; o <<= 1) {
        u32 t = (tid >= o) ? sc[tid - o] : 0u;
        __syncthreads(); sc[tid] += t; __syncthreads();
    }
    if (tid < NBUK) baseD[tid] = sc[tid] - v;
    __syncthreads();
    v = (tid < NBUK) ? totS[tid] : 0u;
    sc[tid] = v;
    __syncthreads();
    for (int o = 1; o < 256; o <<= 1) {
        u32 t = (tid >= o) ? sc[tid - o] : 0u;
        __syncthreads(); sc[tid] += t; __syncthreads();
    }
    if (tid < NBUK) baseS[tid] = sc[tid] - v;
    if (tid == 0) rs[N_NODES] = N_EDGES;
}

// ---- phase 3: place edges into bucket runs (contiguous per (block,bucket))
__global__ __launch_bounds__(256)
void p3_kernel(const int* __restrict__ src, const int* __restrict__ dst,
               const u32* __restrict__ cntD, const u32* __restrict__ cntS,
               const u32* __restrict__ baseD, const u32* __restrict__ baseS,
               int2* __restrict__ db, int* __restrict__ sb) {
    __shared__ u32 od[NBUK], os[NBUK];
    int b = blockIdx.x, tid = threadIdx.x;
    if (tid < NBUK) {
        od[tid] = baseD[tid] + cntD[b * NBUK + tid];
        os[tid] = baseS[tid] + cntS[b * NBUK + tid];
    }
    __syncthreads();
    int lo = b * EPB, hi = lo + EPB;
    for (int e = lo + tid; e < hi; e += 256) {
        int s = src[e], d = dst[e];
        u32 p = atomicAdd(&od[d >> 8], 1u);
        db[p] = make_int2(s, d);
        u32 q = atomicAdd(&os[s >> 8], 1u);
        sb[q] = s;
    }
}

// ---- phase 4d: per-bucket CSR finalize (in-deg -> nd, rs, es placement)
__global__ __launch_bounds__(256)
void p4d_kernel(const int2* __restrict__ db, const u32* __restrict__ totD,
                const u32* __restrict__ baseD, float* __restrict__ nd,
                u32* __restrict__ rs, int* __restrict__ es) {
    __shared__ u32 hist[256], sc[256], off[256];
    int k = blockIdx.x, tid = threadIdx.x;
    hist[tid] = 0;
    __syncthreads();
    u32 nEd = totD[k], base = baseD[k];
    for (u32 i = tid; i < nEd; i += 256)
        atomicAdd(&hist[db[base + i].y & 255], 1u);
    __syncthreads();
    u32 v = hist[tid];
    sc[tid] = v;
    __syncthreads();
    for (int o = 1; o < 256; o <<= 1) {
        u32 t = (tid >= o) ? sc[tid - o] : 0u;
        __syncthreads(); sc[tid] += t; __syncthreads();
    }
    u32 pf = sc[tid] - v;
    int node = k * 256 + tid;
    if (node < N_NODES) {
        rs[node] = base + pf;
        u32 c = v < 1u ? 1u : v;
        nd[node] = rsqrtf((float)c);
    }
    off[tid] = base + pf;
    __syncthreads();
    for (u32 i = tid; i < nEd; i += 256) {
        int2 p = db[base + i];
        u32 pos = atomicAdd(&off[p.y & 255], 1u);
        es[pos] = p.x;
    }
}

// ---- phase 4s: per-bucket out-degree -> ns
__global__ __launch_bounds__(256)
void p4s_kernel(const int* __restrict__ sb, const u32* __restrict__ totS,
                const u32* __restrict__ baseS, float* __restrict__ ns) {
    __shared__ u32 hist[256];
    int k = blockIdx.x, tid = threadIdx.x;
    hist[tid] = 0;
    __syncthreads();
    u32 n = totS[k], base = baseS[k];
    for (u32 i = tid; i < n; i += 256)
        atomicAdd(&hist[sb[base + i] & 255], 1u);
    __syncthreads();
    int node = k * 256 + tid;
    if (node < N_NODES) {
        u32 c = hist[tid]; if (c < 1u) c = 1u;
        ns[node] = rsqrtf((float)c);
    }
}

// ---- hS(bf16) = feat * ns[row]
__global__ __launch_bounds__(256)
void prescale_kernel(const float* __restrict__ feat, const float* __restrict__ ns,
                     u16* __restrict__ hS) {
    int i = blockIdx.x * 256 + threadIdx.x;      // over N_NODES*32 float4 chunks
    if (i < N_NODES * 32) {
        float s = ns[i >> 5];
        float4 v = *(const float4*)&feat[(size_t)i * 4];
        uint2 o;
        o.x = packbf2(s * v.x, s * v.y);
        o.y = packbf2(s * v.z, s * v.w);
        *(uint2*)&hS[(size_t)i * 4] = o;
    }
}

// ---- 128-wide bf16 gather-aggregate, bf16 out; 1 wave/node,
//      quarter-wave = 1 edge row (16 lanes x uint4 = 256B), 16 edges/main iter
__global__ __launch_bounds__(256)
void agg128_kernel(const u16* __restrict__ h, const u32* __restrict__ rs,
                   const int* __restrict__ es, u16* __restrict__ agg) {
    int node = blockIdx.x * 4 + (threadIdx.x >> 6);
    int lane = threadIdx.x & 63;
    int quarter = lane >> 4;
    int q = lane & 15;                    // uint4 chunk (8 bf16) within row
    const uint4* hp = (const uint4*)h;    // row = 16 uint4
    u32 s0 = rs[node], s1 = rs[node + 1];
    float acc[8] = {0.f, 0.f, 0.f, 0.f, 0.f, 0.f, 0.f, 0.f};
    u32 i = s0;
    for (; i + 16 <= s1; i += 16) {
        int e0 = es[i + quarter],     e1 = es[i + 4 + quarter];
        int e2 = es[i + 8 + quarter], e3 = es[i + 12 + quarter];
        uint4 a = hp[(size_t)e0 * 16 + q];
        uint4 b = hp[(size_t)e1 * 16 + q];
        uint4 c = hp[(size_t)e2 * 16 + q];
        uint4 d = hp[(size_t)e3 * 16 + q];
        acc[0] += (bflo(a.x) + bflo(b.x)) + (bflo(c.x) + bflo(d.x));
        acc[1] += (bfhi(a.x) + bfhi(b.x)) + (bfhi(c.x) + bfhi(d.x));
        acc[2] += (bflo(a.y) + bflo(b.y)) + (bflo(c.y) + bflo(d.y));
        acc[3] += (bfhi(a.y) + bfhi(b.y)) + (bfhi(c.y) + bfhi(d.y));
        acc[4] += (bflo(a.z) + bflo(b.z)) + (bflo(c.z) + bflo(d.z));
        acc[5] += (bfhi(a.z) + bfhi(b.z)) + (bfhi(c.z) + bfhi(d.z));
        acc[6] += (bflo(a.w) + bflo(b.w)) + (bflo(c.w) + bflo(d.w));
        acc[7] += (bfhi(a.w) + bfhi(b.w)) + (bfhi(c.w) + bfhi(d.w));
    }
    for (; i + 4 <= s1; i += 4) {
        uint4 a = hp[(size_t)es[i + quarter] * 16 + q];
        acc[0] += bflo(a.x); acc[1] += bfhi(a.x);
        acc[2] += bflo(a.y); acc[3] += bfhi(a.y);
        acc[4] += bflo(a.z); acc[5] += bfhi(a.z);
        acc[6] += bflo(a.w); acc[7] += bfhi(a.w);
    }
    u32 rem = s1 - i;
    if ((u32)quarter < rem) {
        uint4 a = hp[(size_t)es[i + quarter] * 16 + q];
        acc[0] += bflo(a.x); acc[1] += bfhi(a.x);
        acc[2] += bflo(a.y); acc[3] += bfhi(a.y);
        acc[4] += bflo(a.z); acc[5] += bfhi(a.z);
        acc[6] += bflo(a.w); acc[7] += bfhi(a.w);
    }
    #pragma unroll
    for (int j = 0; j < 8; ++j) {
        acc[j] += __shfl_xor(acc[j], 16, 64);
        acc[j] += __shfl_xor(acc[j], 32, 64);
    }
    if (lane < 16) {
        uint4 pk;
        pk.x = packbf2(acc[0], acc[1]);
        pk.y = packbf2(acc[2], acc[3]);
        pk.z = packbf2(acc[4], acc[5]);
        pk.w = packbf2(acc[6], acc[7]);
        *(uint4*)&agg[(size_t)node * 128 + q * 8] = pk;
    }
}

// ---- MFMA GEMM: A bf16 [50000][128], W f32 [128][NCOL] -> C bf16 [50000][NCOL]
// block = 256 thr (4 waves), 64 rows/block; wave = 16 rows x NCOL.
// MODE 0: C = ns*relu(nd*acc + b); MODE 1: C = acc
template <int NCOL, int MODE>
__global__ __launch_bounds__(256)
void mfma_gemm_kernel(const u16* __restrict__ Ab, const float* __restrict__ W,
                      const float* __restrict__ bias, const float* __restrict__ ns,
                      const float* __restrict__ nd, u16* __restrict__ C) {
    constexpr int NT = NCOL / 16;          // MFMA n-tiles per wave
    constexpr int WROW = 136;              // u16 row stride (+8 pad: 2-way only)
    constexpr int CROW = NCOL + 4;         // f32 row stride of C staging
    __shared__ u16 Wt[NCOL * WROW];        // W transposed: Wt[c][k]
    __shared__ float Cl[4][16 * CROW];
    int tid = threadIdx.x;
    int w = tid >> 6, lane = tid & 63;
    int rowbase = blockIdx.x * 64 + w * 16;

    // stage Wt[c][k] = bf16(W[k][c]) — read coalesced, scatter to LDS
    for (int i = tid; i < 128 * NCOL; i += 256) {
        int k = i / NCOL, c = i % NCOL;
        Wt[c * WROW + k] = (u16)f2bf(W[i]);
    }
    __syncthreads();

    int m = lane & 15, kb = lane >> 4;     // A row / k-block within 32-k step
    int arow = rowbase + m;
    if (arow > N_NODES - 1) arow = N_NODES - 1;   // clamp (invalid rows unstored)
    f32x4 acc[NT];
    #pragma unroll
    for (int nt = 0; nt < NT; ++nt) acc[nt] = (f32x4){0.f, 0.f, 0.f, 0.f};

    #pragma unroll
    for (int ks = 0; ks < 4; ++ks) {       // K = 128 = 4 x 32
        int k0 = ks * 32 + kb * 8;
        bf16x8 a = *(const bf16x8*)&Ab[(size_t)arow * 128 + k0];
        #pragma unroll
        for (int nt = 0; nt < NT; ++nt) {
            bf16x8 b = *(const bf16x8*)&Wt[(nt * 16 + m) * WROW + k0];
            acc[nt] = __builtin_amdgcn_mfma_f32_16x16x32_bf16(a, b, acc[nt], 0, 0, 0);
        }
    }

    // stage C tile: D layout col = lane&15 (m), row = kb*4 + reg (m89-verified)
    #pragma unroll
    for (int nt = 0; nt < NT; ++nt)
        #pragma unroll
        for (int reg = 0; reg < 4; ++reg)
            Cl[w][(kb * 4 + reg) * CROW + nt * 16 + m] = acc[nt][reg];
    __syncthreads();

    // epilogue: coalesced read-back, scale/bias/relu, packed bf16 store
    constexpr int CQ = NCOL / 4;
    for (int i = lane; i < 16 * CQ; i += 64) {
        int r = i / CQ, c4 = (i % CQ) * 4;
        int row = rowbase + r;
        if (row < N_NODES) {
            float4 o = *(float4*)&Cl[w][r * CROW + c4];
            if (MODE == 0) {
                float sd = nd[row], ss = ns[row];
                o.x = ss * fmaxf(sd * o.x + bias[c4 + 0], 0.f);
                o.y = ss * fmaxf(sd * o.y + bias[c4 + 1], 0.f);
                o.z = ss * fmaxf(sd * o.z + bias[c4 + 2], 0.f);
                o.w = ss * fmaxf(sd * o.w + bias[c4 + 3], 0.f);
            }
            uint2 pk = {packbf2(o.x, o.y), packbf2(o.z, o.w)};
            *(uint2*)&C[(size_t)row * NCOL + c4] = pk;
        }
    }
}

// ---- fused layer-3 aggregate + heads: gather t (64-wide bf16),
//      h4 = nd*agg + b3; PI = h4.Wp + bp; V partial = sum h4.Wv per block.
__global__ __launch_bounds__(256)
void l3head_kernel(const u16* __restrict__ t, const u32* __restrict__ rs,
                   const int* __restrict__ es, const float* __restrict__ nd,
                   const float* __restrict__ b3, const float* __restrict__ Wp,
                   const float* __restrict__ Wv, const float* __restrict__ bp,
                   float* __restrict__ out, float* __restrict__ vpart) {
    __shared__ float sv;
    if (threadIdx.x == 0) sv = 0.f;
    __syncthreads();
    int lane = threadIdx.x & 63;
    int wvid = threadIdx.x >> 6;
    int quarter = lane >> 4;
    int q = lane & 15;
    const uint2* hp = (const uint2*)t;      // row = 16 uint2
    float4 b3v = ((const float4*)b3)[q];
    float4 wpv = ((const float4*)Wp)[q];
    float4 wvv = ((const float4*)Wv)[q];
    float bpv = bp[0];
    float vacc = 0.f;
    for (int n = blockIdx.x * 4 + wvid; n < N_NODES; n += HEAD_BLOCKS * 4) {
        u32 s0 = rs[n], s1 = rs[n + 1];
        float4 acc = {0.f, 0.f, 0.f, 0.f};
        u32 i = s0;
        for (; i + 8 <= s1; i += 8) {
            int e0 = es[i + quarter], e1 = es[i + 4 + quarter];
            uint2 a = hp[(size_t)e0 * 16 + q];
            uint2 b = hp[(size_t)e1 * 16 + q];
            acc.x += bflo(a.x) + bflo(b.x);
            acc.y += bfhi(a.x) + bfhi(b.x);
            acc.z += bflo(a.y) + bflo(b.y);
            acc.w += bfhi(a.y) + bfhi(b.y);
        }
        for (; i + 4 <= s1; i += 4) {
            int e = es[i + quarter];
            uint2 a = hp[(size_t)e * 16 + q];
            acc.x += bflo(a.x); acc.y += bfhi(a.x);
            acc.z += bflo(a.y); acc.w += bfhi(a.y);
        }
        u32 rem = s1 - i;
        if ((u32)quarter < rem) {
            int e = es[i + quarter];
            uint2 a = hp[(size_t)e * 16 + q];
            acc.x += bflo(a.x); acc.y += bfhi(a.x);
            acc.z += bflo(a.y); acc.w += bfhi(a.y);
        }
        acc.x += __shfl_xor(acc.x, 16, 64); acc.x += __shfl_xor(acc.x, 32, 64);
        acc.y += __shfl_xor(acc.y, 16, 64); acc.y += __shfl_xor(acc.y, 32, 64);
        acc.z += __shfl_xor(acc.z, 16, 64); acc.z += __shfl_xor(acc.z, 32, 64);
        acc.w += __shfl_xor(acc.w, 16, 64); acc.w += __shfl_xor(acc.w, 32, 64);
        float ndv = nd[n];
        float4 h;
        h.x = ndv * acc.x + b3v.x;
        h.y = ndv * acc.y + b3v.y;
        h.z = ndv * acc.z + b3v.z;
        h.w = ndv * acc.w + b3v.w;
        float p  = h.x * wpv.x + h.y * wpv.y + h.z * wpv.z + h.w * wpv.w;
        float vv = h.x * wvv.x + h.y * wvv.y + h.z * wvv.z + h.w * wvv.w;
        p  += __shfl_xor(p, 1, 64);  p  += __shfl_xor(p, 2, 64);
        p  += __shfl_xor(p, 4, 64);  p  += __shfl_xor(p, 8, 64);
        vv += __shfl_xor(vv, 1, 64); vv += __shfl_xor(vv, 2, 64);
        vv += __shfl_xor(vv, 4, 64); vv += __shfl_xor(vv, 8, 64);
        if (lane == 0) { out[n] = p + bpv; vacc += vv; }
    }
    if (lane == 0) atomicAdd(&sv, vacc);
    __syncthreads();
    if (threadIdx.x == 0) vpart[blockIdx.x] = sv;
}

// ---- final V reduction over block partials
__global__ __launch_bounds__(256)
void vred_kernel(const float* __restrict__ vpart, const float* __restrict__ bv,
                 float* __restrict__ out) {
    float v = 0.f;
    for (int i = threadIdx.x; i < HEAD_BLOCKS; i += 256) v += vpart[i];
    #pragma unroll
    for (int off = 32; off; off >>= 1) v += __shfl_down(v, off, 64);
    __shared__ float s[4];
    if ((threadIdx.x & 63) == 0) s[threadIdx.x >> 6] = v;
    __syncthreads();
    if (threadIdx.x == 0) out[N_NODES] = s[0] + s[1] + s[2] + s[3] + bv[0];
}

extern "C" void kernel_launch(void* const* d_in, const int* in_sizes, int n_in,
                              void* d_out, int out_size, void* d_ws, size_t ws_size,
                              hipStream_t stream) {
    const float* feat = (const float*)d_in[0];
    const int*   src  = (const int*)d_in[1];
    const int*   dst  = (const int*)d_in[2];
    const float* W0 = (const float*)d_in[3];  const float* b0 = (const float*)d_in[4];
    const float* W1 = (const float*)d_in[5];  const float* b1 = (const float*)d_in[6];
    const float* W2 = (const float*)d_in[7];  const float* b2 = (const float*)d_in[8];
    const float* W3 = (const float*)d_in[9];  const float* b3 = (const float*)d_in[10];
    const float* Wp = (const float*)d_in[11]; const float* bp = (const float*)d_in[12];
    const float* Wv = (const float*)d_in[13]; const float* bv = (const float*)d_in[14];
    float* out = (float*)d_out;
    char*  wsb = (char*)d_ws;

    float* ns    = (float*)(wsb + OFF_NS);
    float* nd    = (float*)(wsb + OFF_ND);
    u32*   rs    = (u32*)(wsb + OFF_RS);
    int*   es    = (int*)(wsb + OFF_ES);
    u32*   cntD  = (u32*)(wsb + OFF_CNTD);
    u32*   cntS  = (u32*)(wsb + OFF_CNTS);
    u32*   totD  = (u32*)(wsb + OFF_TOTD);
    u32*   totS  = (u32*)(wsb + OFF_TOTS);
    u32*   baseD = (u32*)(wsb + OFF_BASED);
    u32*   baseS = (u32*)(wsb + OFF_BASES);
    float* vpart = (float*)(wsb + OFF_VP);
    int2*  db    = (int2*)(wsb + OFF_DB);
    int*   sb    = (int*)(wsb + OFF_SB);
    u16*   T0    = (u16*)(wsb + OFF_T0);
    u16*   T1    = (u16*)(wsb + OFF_T1);
    u16*   TA    = (u16*)(wsb + OFF_TA);
    u16*   Tt    = (u16*)(wsb + OFF_TT);

    p1_kernel<<<NBLK, 256, 0, stream>>>(src, dst, cntD, cntS);
    p2a_kernel<<<NBUK, 256, 0, stream>>>(cntD, cntS, totD, totS);
    p2b_kernel<<<1, 256, 0, stream>>>(totD, totS, baseD, baseS, rs);
    p3_kernel<<<NBLK, 256, 0, stream>>>(src, dst, cntD, cntS, baseD, baseS, db, sb);
    p4d_kernel<<<NBUK, 256, 0, stream>>>(db, totD, baseD, nd, rs, es);
    p4s_kernel<<<NBUK, 256, 0, stream>>>(sb, totS, baseS, ns);

    prescale_kernel<<<6250, 256, 0, stream>>>(feat, ns, T0);

    // layer 0
    agg128_kernel<<<12500, 256, 0, stream>>>(T0, rs, es, TA);
    mfma_gemm_kernel<128, 0><<<782, 256, 0, stream>>>(TA, W0, b0, ns, nd, T1);
    // layer 1
    agg128_kernel<<<12500, 256, 0, stream>>>(T1, rs, es, TA);
    mfma_gemm_kernel<128, 0><<<782, 256, 0, stream>>>(TA, W1, b1, ns, nd, T0);
    // layer 2
    agg128_kernel<<<12500, 256, 0, stream>>>(T0, rs, es, TA);
    mfma_gemm_kernel<128, 0><<<782, 256, 0, stream>>>(TA, W2, b2, ns, nd, T1);  // h3s
    // layer 3: transform first (128->64), then fused aggregate+heads
    mfma_gemm_kernel<64, 1><<<782, 256, 0, stream>>>(T1, W3, b3, ns, nd, Tt);
    l3head_kernel<<<HEAD_BLOCKS, 256, 0, stream>>>(Tt, rs, es, nd, b3, Wp, Wv, bp, out, vpart);
    vred_kernel<<<1, 256, 0, stream>>>(vpart, bv, out);
}